// Round 5
// baseline (1078.823 us; speedup 1.0000x reference)
//
#include <hip/hip_runtime.h>
#include <hip/hip_bf16.h>
#include <math.h>

#define BB 4096
#define TT 200
#define EE 64

// ws float layout:
//  [0,5120)            WkC = W1[64:128]-W1[128:192]   (64x80)
//  [5120,10240)        WqC = W1[0:64]+W1[128:192]     (64x80)
//  [10240,337920)      qW  = targets@WqC + b1         (B x 80)
//  [337920,1157120)    logits  [T][B]
//  [1157120,1976320)   scores  [T][B]   (fallback path)
//  [1976320,2795520)   scoresT [B][T]   (fast path, sequential s_loads)
//  [2795520,4433920)   xg  [B][T][2]    {x@Wu1+bu, x@Wr1+br}
//  [4433920,56862720)  xcA [B][16][T][4]  x@Wc1+bc, float4-tiled for coalescing

#define WS_FAST_FLOATS 56862720ull

__device__ __forceinline__ float lane_bcast(float v, int l) {
    return __int_as_float(__builtin_amdgcn_readlane(__float_as_int(v), l));
}

__global__ __launch_bounds__(256) void prep_kernel(const float* __restrict__ W1,
                                                   float* __restrict__ ws) {
    int idx = blockIdx.x * 256 + threadIdx.x;   // i*80+j, i<64
    if (idx >= 64 * 80) return;
    float wa = W1[idx];
    float wb = W1[64 * 80 + idx];
    float wc = W1[128 * 80 + idx];
    ws[idx]        = wb - wc;   // WkC
    ws[5120 + idx] = wa + wc;   // WqC
}

__global__ __launch_bounds__(256) void qw_kernel(const float* __restrict__ targets,
                                                 const float* __restrict__ b1,
                                                 const float* __restrict__ ws,
                                                 float* __restrict__ qW) {
    int idx = blockIdx.x * 256 + threadIdx.x;   // b*80+j
    int b = idx / 80;
    int j = idx - b * 80;
    const float* q  = targets + (size_t)b * 64;
    const float* Wq = ws + 5120;
    float s = b1[j];
#pragma unroll
    for (int i = 0; i < 64; i++) s = fmaf(q[i], Wq[i * 80 + j], s);
    qW[idx] = s;
}

// one thread per (b,t): logit via restructured MLP (LDS-broadcast weights)
__global__ __launch_bounds__(256) void mlp_kernel(
    const float* __restrict__ gru, const float* __restrict__ targets,
    const float* __restrict__ W1, const float* __restrict__ W2,
    const float* __restrict__ b2, const float* __restrict__ Wf,
    const float* __restrict__ bf, const float* __restrict__ ws,
    float* __restrict__ logits) {
    __shared__ float4 sWk[1280];   // [64][20 quads]
    __shared__ float4 sWp[1280];
    const float4* WkC = (const float4*)ws;              // 5120 floats
    const float4* Wp  = (const float4*)(W1 + 192 * 80); // last 64 rows of W1
    for (int i = threadIdx.x; i < 1280; i += 256) {
        sWk[i] = WkC[i];
        sWp[i] = Wp[i];
    }
    __syncthreads();

    int idx = blockIdx.x * 256 + threadIdx.x;   // exactly B*T threads
    int b = idx / 200;
    int t = idx - b * 200;
    const float4* kp  = (const float4*)(gru + ((size_t)b * 200 + t) * 64);
    const float4* qp  = (const float4*)(targets + (size_t)b * 64);
    const float4* qWv = (const float4*)(ws + 10240 + (size_t)b * 80);

    float4 h1[20];
#pragma unroll
    for (int j = 0; j < 20; j++) h1[j] = qWv[j];

    for (int i4 = 0; i4 < 16; i4++) {
        float4 kv = kp[i4];
        float4 qv = qp[i4];
        float kk[4] = {kv.x, kv.y, kv.z, kv.w};
        float pp[4] = {qv.x * kv.x, qv.y * kv.y, qv.z * kv.z, qv.w * kv.w};
#pragma unroll
        for (int u = 0; u < 4; u++) {
            const float4* wk = &sWk[(i4 * 4 + u) * 20];
            const float4* wp = &sWp[(i4 * 4 + u) * 20];
            float ki = kk[u], pi = pp[u];
#pragma unroll
            for (int j = 0; j < 20; j++) {
                float4 a = wk[j], c = wp[j];
                h1[j].x = fmaf(ki, a.x, fmaf(pi, c.x, h1[j].x));
                h1[j].y = fmaf(ki, a.y, fmaf(pi, c.y, h1[j].y));
                h1[j].z = fmaf(ki, a.z, fmaf(pi, c.z, h1[j].z));
                h1[j].w = fmaf(ki, a.w, fmaf(pi, c.w, h1[j].w));
            }
        }
    }
    // layer 2: 80 -> 40
    float4 h2[10];
    const float4* b2v = (const float4*)b2;
    const float4* W2v = (const float4*)W2;   // [80][10 quads]
#pragma unroll
    for (int j = 0; j < 10; j++) h2[j] = b2v[j];
#pragma unroll
    for (int iq = 0; iq < 20; iq++) {
        float4 hv = h1[iq];
        float hs[4] = {hv.x, hv.y, hv.z, hv.w};
#pragma unroll
        for (int u = 0; u < 4; u++) {
            float v = hs[u];
            const float4* wr = W2v + (iq * 4 + u) * 10;
#pragma unroll
            for (int j = 0; j < 10; j++) {
                float4 w = wr[j];
                h2[j].x = fmaf(v, w.x, h2[j].x);
                h2[j].y = fmaf(v, w.y, h2[j].y);
                h2[j].z = fmaf(v, w.z, h2[j].z);
                h2[j].w = fmaf(v, w.w, h2[j].w);
            }
        }
    }
    // final: 40 -> 1
    const float4* Wfv = (const float4*)Wf;
    float lg = bf[0];
#pragma unroll
    for (int j = 0; j < 10; j++) {
        float4 w = Wfv[j];
        lg = fmaf(h2[j].x, w.x, lg);
        lg = fmaf(h2[j].y, w.y, lg);
        lg = fmaf(h2[j].z, w.z, lg);
        lg = fmaf(h2[j].w, w.w, lg);
    }
    if (lg == 0.0f) lg = -INFINITY;
    logits[(size_t)t * BB + b] = lg;
}

// softmax over batch dim for each t; writes both [T][B] and transposed [B][T]
__global__ __launch_bounds__(256) void softmax_kernel(const float* __restrict__ logits,
                                                      float* __restrict__ scores,
                                                      float* __restrict__ scoresT) {
    int t = blockIdx.x;
    int tid = threadIdx.x;
    const float* L = logits + (size_t)t * BB;
    float v[16];
#pragma unroll
    for (int i = 0; i < 16; i++) {
        float x = L[tid + i * 256];
        v[i] = (x == 0.0f) ? -INFINITY : x;
    }
    float m = v[0];
#pragma unroll
    for (int i = 1; i < 16; i++) m = fmaxf(m, v[i]);
#pragma unroll
    for (int off = 32; off; off >>= 1) m = fmaxf(m, __shfl_xor(m, off));
    __shared__ float sm[4];
    __shared__ float ss[4];
    int wid = tid >> 6;
    if ((tid & 63) == 0) sm[wid] = m;
    __syncthreads();
    m = fmaxf(fmaxf(sm[0], sm[1]), fmaxf(sm[2], sm[3]));
    float e[16];
    float s = 0.0f;
#pragma unroll
    for (int i = 0; i < 16; i++) {
        e[i] = __expf(v[i] - m);
        s += e[i];
    }
#pragma unroll
    for (int off = 32; off; off >>= 1) s += __shfl_xor(s, off);
    if ((tid & 63) == 0) ss[wid] = s;
    __syncthreads();
    s = ss[0] + ss[1] + ss[2] + ss[3];
    float inv = 1.0f / s;
    float* S = scores + (size_t)t * BB;
#pragma unroll
    for (int i = 0; i < 16; i++) {
        float sc = e[i] * inv;
        S[tid + i * 256] = sc;
        scoresT[(size_t)(tid + i * 256) * TT + t] = sc;
    }
}

// x-precompute: per (b,t) compute xc[j] = bc[j] + x@Wc1[:,j] (j<64),
// xg = {x@Wu1+bu, x@Wr1+br}. One thread per (b,t), weights LDS-broadcast.
// xcA layout [b][j4][t][4] so stores are fully coalesced over t.
__global__ __launch_bounds__(256) void xcpre_kernel(
    const float* __restrict__ gru, const float* __restrict__ Wc,
    const float* __restrict__ bc, const float* __restrict__ Wu,
    const float* __restrict__ bu, const float* __restrict__ Wr,
    const float* __restrict__ br, float* __restrict__ xcA,
    float* __restrict__ xg) {
    __shared__ float sW[64 * 64];   // Wc1 rows
    __shared__ float sG[128];       // wu1 | wr1
    for (int i = threadIdx.x; i < 4096; i += 256) sW[i] = Wc[i];
    if (threadIdx.x < 64) sG[threadIdx.x] = Wu[threadIdx.x];
    else if (threadIdx.x < 128) sG[threadIdx.x] = Wr[threadIdx.x - 64];
    __syncthreads();

    int idx = blockIdx.x * 256 + threadIdx.x;
    int b = idx / 200;
    int t = idx - b * 200;
    const float4* xp  = (const float4*)(gru + ((size_t)b * 200 + t) * 64);
    const float4* bc4 = (const float4*)bc;

    float4 acc[16];
#pragma unroll
    for (int j = 0; j < 16; j++) acc[j] = bc4[j];   // uniform -> s_load
    float gu = bu[0], gr = br[0];

    for (int i4 = 0; i4 < 16; i4++) {
        float4 xv = xp[i4];
        float xs[4] = {xv.x, xv.y, xv.z, xv.w};
#pragma unroll
        for (int u = 0; u < 4; u++) {
            int i = i4 * 4 + u;
            float xi = xs[u];
            const float4* wr_ = (const float4*)(sW + i * 64);
#pragma unroll
            for (int j = 0; j < 16; j++) {
                float4 w = wr_[j];
                acc[j].x = fmaf(xi, w.x, acc[j].x);
                acc[j].y = fmaf(xi, w.y, acc[j].y);
                acc[j].z = fmaf(xi, w.z, acc[j].z);
                acc[j].w = fmaf(xi, w.w, acc[j].w);
            }
            gu = fmaf(xi, sG[i], gu);
            gr = fmaf(xi, sG[64 + i], gr);
        }
    }
    float4* xc4 = (float4*)xcA;
#pragma unroll
    for (int j4 = 0; j4 < 16; j4++)
        xc4[((size_t)b * 16 + j4) * TT + t] = acc[j4];   // coalesced over t
    float2* xg2 = (float2*)xg;
    xg2[(size_t)b * TT + t] = make_float2(gu, gr);        // coalesced
}

// Recurrence only: one wave per b, lane j owns h[j] and column j of Wc2.
// Weights PINNED in VGPRs via asm (defeats load-sinking). Single-wave block:
// no __syncthreads, so the xc/xg/score streams software-pipeline freely.
__global__ __launch_bounds__(64) void rec_kernel(
    const float* __restrict__ xcA, const float* __restrict__ xg,
    const float* __restrict__ scoresT, const float* __restrict__ Wc,
    const float* __restrict__ Wu, const float* __restrict__ Wr,
    float* __restrict__ out) {
    const int lane = threadIdx.x;
    const int b = blockIdx.x;

    float wc2[64];
#pragma unroll
    for (int k = 0; k < 64; k++) {
        wc2[k] = Wc[(64 + k) * 64 + lane];
        asm volatile("" : "+v"(wc2[k]));   // pin in VGPR, forbid remat/sink
    }
    float wu2 = Wu[64 + lane], wr2 = Wr[64 + lane];
    asm volatile("" : "+v"(wu2), "+v"(wr2));

    const float* xcp = xcA + ((size_t)b * 16 + (lane >> 2)) * (TT * 4) + (lane & 3);
    const float* xgp = xg + (size_t)b * TT * 2;       // uniform -> s_load
    const float* scp = scoresT + (size_t)b * TT;      // uniform -> s_load

    float h = 0.0f;
    for (int t = 0; t < TT; t++) {
        float xc  = xcp[t * 4];        // per-lane coalesced dword
        float xgu = xgp[2 * t];        // includes bu
        float xgr = xgp[2 * t + 1];    // includes br
        float sc  = scp[t];
        float pu = h * wu2;
        float pr = h * wr2;
#pragma unroll
        for (int off = 32; off; off >>= 1) {
            pu += __shfl_xor(pu, off);
            pr += __shfl_xor(pr, off);
        }
        float u = sc / (1.0f + __expf(-(pu + xgu)));
        float r = 1.0f / (1.0f + __expf(-(pr + xgr)));
        float a0 = 0.0f, a1 = 0.0f, a2 = 0.0f, a3 = 0.0f;
#pragma unroll
        for (int k = 0; k < 16; k++) {
            a0 = fmaf(lane_bcast(h, 4 * k + 0), wc2[4 * k + 0], a0);
            a1 = fmaf(lane_bcast(h, 4 * k + 1), wc2[4 * k + 1], a1);
            a2 = fmaf(lane_bcast(h, 4 * k + 2), wc2[4 * k + 2], a2);
            a3 = fmaf(lane_bcast(h, 4 * k + 3), wc2[4 * k + 3], a3);
        }
        float arg = xc + r * ((a0 + a1) + (a2 + a3));
        float ex = __expf(2.0f * arg);                // tanh
        float th = 1.0f - 2.0f / (ex + 1.0f);
        h = fmaf(u, th - h, h);
    }
    out[(size_t)b * 64 + lane] = h;
}

// Fallback (small ws): R4 producer/consumer with pinned weights.
__global__ __launch_bounds__(128, 4) void augru_kernel(
    const float* __restrict__ gru, const float* __restrict__ scores,
    const float* __restrict__ Wu, const float* __restrict__ bu,
    const float* __restrict__ Wr, const float* __restrict__ br,
    const float* __restrict__ Wc, const float* __restrict__ bc,
    float* __restrict__ out) {
    __shared__ float sxc[2][64];
    __shared__ float sxg[2][2];
    const int lane = threadIdx.x & 63;
    const int wid  = threadIdx.x >> 6;
    const int b    = blockIdx.x;
    const float* xrow = gru + (size_t)b * TT * 64;

    if (wid == 0) {
        float wc1[64];
#pragma unroll
        for (int k = 0; k < 64; k++) {
            wc1[k] = Wc[k * 64 + lane];
            asm volatile("" : "+v"(wc1[k]));
        }
        float wu1l = Wu[lane], wr1l = Wr[lane];
        float bcl = bc[lane];

        auto produce = [&](int tp, float xl) {
            float pu = xl * wu1l;
            float pr = xl * wr1l;
#pragma unroll
            for (int off = 32; off; off >>= 1) {
                pu += __shfl_xor(pu, off);
                pr += __shfl_xor(pr, off);
            }
            float a0 = bcl, a1 = 0.0f, a2 = 0.0f, a3 = 0.0f;
#pragma unroll
            for (int k = 0; k < 16; k++) {
                a0 = fmaf(lane_bcast(xl, 4 * k + 0), wc1[4 * k + 0], a0);
                a1 = fmaf(lane_bcast(xl, 4 * k + 1), wc1[4 * k + 1], a1);
                a2 = fmaf(lane_bcast(xl, 4 * k + 2), wc1[4 * k + 2], a2);
                a3 = fmaf(lane_bcast(xl, 4 * k + 3), wc1[4 * k + 3], a3);
            }
            int p = tp & 1;
            sxc[p][lane] = (a0 + a1) + (a2 + a3);
            if (lane == 0) sxg[p][0] = pu;
            if (lane == 1) sxg[p][1] = pr;
        };

        float xl = xrow[lane];
        produce(0, xl);
        xl = xrow[64 + lane];
        __syncthreads();
        for (int t = 0; t < TT; t++) {
            if (t + 1 < TT) {
                float xnn = (t + 2 < TT) ? xrow[(size_t)(t + 2) * 64 + lane] : 0.0f;
                produce(t + 1, xl);
                xl = xnn;
            }
            __syncthreads();
        }
    } else {
        float wc2[64];
#pragma unroll
        for (int k = 0; k < 64; k++) {
            wc2[k] = Wc[(64 + k) * 64 + lane];
            asm volatile("" : "+v"(wc2[k]));
        }
        float wu2l = Wu[64 + lane], wr2l = Wr[64 + lane];
        float sbu = bu[0], sbr = br[0];
        float h = 0.0f;
        __syncthreads();
        for (int t = 0; t < TT; t++) {
            int p = t & 1;
            float sc = scores[(size_t)t * BB + b];
            float xc = sxc[p][lane];
            float xu = sxg[p][0];
            float xv = sxg[p][1];
            float pu = h * wu2l;
            float pr = h * wr2l;
#pragma unroll
            for (int off = 32; off; off >>= 1) {
                pu += __shfl_xor(pu, off);
                pr += __shfl_xor(pr, off);
            }
            float u = sc / (1.0f + __expf(-(pu + xu + sbu)));
            float r = 1.0f / (1.0f + __expf(-(pr + xv + sbr)));
            float a0 = 0.0f, a1 = 0.0f, a2 = 0.0f, a3 = 0.0f;
#pragma unroll
            for (int k = 0; k < 16; k++) {
                a0 = fmaf(lane_bcast(h, 4 * k + 0), wc2[4 * k + 0], a0);
                a1 = fmaf(lane_bcast(h, 4 * k + 1), wc2[4 * k + 1], a1);
                a2 = fmaf(lane_bcast(h, 4 * k + 2), wc2[4 * k + 2], a2);
                a3 = fmaf(lane_bcast(h, 4 * k + 3), wc2[4 * k + 3], a3);
            }
            float arg = xc + r * ((a0 + a1) + (a2 + a3));
            float ex = __expf(2.0f * arg);
            float th = 1.0f - 2.0f / (ex + 1.0f);
            h = fmaf(u, th - h, h);
            __syncthreads();
        }
        out[(size_t)b * 64 + lane] = h;
    }
}

extern "C" void kernel_launch(void* const* d_in, const int* in_sizes, int n_in,
                              void* d_out, int out_size, void* d_ws, size_t ws_size,
                              hipStream_t stream) {
    const float* gru     = (const float*)d_in[0];
    const float* targets = (const float*)d_in[1];
    const float* W1 = (const float*)d_in[2];
    const float* b1 = (const float*)d_in[3];
    const float* W2 = (const float*)d_in[4];
    const float* b2 = (const float*)d_in[5];
    const float* Wf = (const float*)d_in[6];
    const float* bf = (const float*)d_in[7];
    const float* Wu = (const float*)d_in[8];
    const float* bu = (const float*)d_in[9];
    const float* Wr = (const float*)d_in[10];
    const float* br = (const float*)d_in[11];
    const float* Wc = (const float*)d_in[12];
    const float* bc = (const float*)d_in[13];
    float* out = (float*)d_out;

    float* ws      = (float*)d_ws;
    float* logits  = ws + 337920;
    float* scores  = ws + 1157120;
    float* scoresT = ws + 1976320;
    float* xg      = ws + 2795520;
    float* xcA     = ws + 4433920;

    bool fast = ws_size >= WS_FAST_FLOATS * 4ull;

    prep_kernel<<<20, 256, 0, stream>>>(W1, ws);
    qw_kernel<<<1280, 256, 0, stream>>>(targets, b1, ws, ws + 10240);
    if (fast)
        xcpre_kernel<<<3200, 256, 0, stream>>>(gru, Wc, bc, Wu, bu, Wr, br, xcA, xg);
    mlp_kernel<<<3200, 256, 0, stream>>>(gru, targets, W1, W2, b2, Wf, bf, ws, logits);
    softmax_kernel<<<200, 256, 0, stream>>>(logits, scores, scoresT);
    if (fast)
        rec_kernel<<<4096, 64, 0, stream>>>(xcA, xg, scoresT, Wc, Wu, Wr, out);
    else
        augru_kernel<<<4096, 128, 0, stream>>>(gru, scores, Wu, bu, Wr, br, Wc, bc, out);
}